// Round 11
// baseline (373.400 us; speedup 1.0000x reference)
//
#include <hip/hip_runtime.h>
#include <hip/hip_bf16.h>

// ---------------------------------------------------------------------------
// NextTaskGAT: 2-layer GAT (H=4, C=64, F_IN=256) + FC(256->64).
// Pinned: inputs fp32 (bf16-grid), edge_index int32, dict order, OUTPUT FP32.
// R22 = R19 (best, 324.3) with the GEMM's LDS staging DELETED: skinny GEMM
// (K=256, B 128KB L2-resident) pays 4x {gload_lds -> vmcnt(0) -> barrier ->
// ds_read} serial chains for data L2 already serves. Now each lane loads
// MFMA fragments (16B aligned) straight from global: no LDS, no barriers,
// no drains. Same m89 fragment math (old path's double-XOR made af[i] ==
// A[row][k0+kg*8] -- loaded directly now). Epilogue/ATT = R19 exact.
// CSR = R19 atomic-free counting sort; gather = R11 form; exp2-folded att.
// ---------------------------------------------------------------------------

#define HEADS 4
#define FDIM  256
#define NBK_MAX 2048   // max buckets (n <= 65536); bucket = dst>>5

typedef __attribute__((ext_vector_type(4))) float f32x4;
typedef __attribute__((ext_vector_type(8))) short s16x8;

__device__ __forceinline__ float b2f(unsigned short u) {
    return __uint_as_float((unsigned)u << 16);
}
__device__ __forceinline__ unsigned short f2b(float f) {
    __hip_bfloat16 b = __float2bfloat16(f);
    return *(unsigned short*)&b;
}

__device__ __forceinline__ float fast_exp2(float t) {
#if __has_builtin(__builtin_amdgcn_exp2f)
    return __builtin_amdgcn_exp2f(t);
#else
    return __expf(t * 0.6931471805599453f);
#endif
}

// ---------------------------------------------------------------------------
// Pass 1: per-block bucket histogram (LDS atomics only).
// cnt layout k-major: cnt[k*128 + b]. Grid MUST be <<<128,1024>>> and the
// grid-stride loop must match bscatter exactly (same block -> same edges).
// ---------------------------------------------------------------------------
__global__ void cnt_hist(const int* __restrict__ dstp, int* __restrict__ cnt,
                         int E, int Et, int nbk) {
    __shared__ int lh[NBK_MAX];
    const int tid = threadIdx.x, b = blockIdx.x;
    for (int i = tid; i < NBK_MAX; i += 1024) lh[i] = 0;
    __syncthreads();
    for (int e = b * 1024 + tid; e < Et; e += 131072) {
        int dd = (e < E) ? dstp[e] : (e - E);
        atomicAdd(&lh[dd >> 5], 1);
    }
    __syncthreads();
    for (int k = tid; k < nbk; k += 1024) cnt[k * 128 + b] = lh[k];
}

// ---------------------------------------------------------------------------
// Fused conversions + per-bucket column scan in ONE dispatch.
// Blocks [0, cvtblocks): x->bf16 (x4 vec) | W1^T | W2^T | fcW^T.
// Blocks [cvtblocks, cvtblocks+nbk): block k scans cnt[k][0..127] ->
// in-place exclusive per-block prefix; total -> bHist[k].
// ---------------------------------------------------------------------------
__global__ void cvt_scan(const float* __restrict__ x, unsigned short* __restrict__ xb,
                         const float* __restrict__ W1, unsigned short* __restrict__ Wt1,
                         const float* __restrict__ W2, unsigned short* __restrict__ Wt2,
                         const float* __restrict__ fcW, unsigned short* __restrict__ fcWt,
                         int* __restrict__ cnt, int* __restrict__ bHist,
                         int nx4, int cvtblocks) {
    if ((int)blockIdx.x >= cvtblocks) {
        const int k = (int)blockIdx.x - cvtblocks;
        const int tid = threadIdx.x;
        __shared__ int w0s;
        int v = 0;
        if (tid < 128) v = cnt[k * 128 + tid];
        const int lane = tid & 63;
        int a = v;
#pragma unroll
        for (int d = 1; d < 64; d <<= 1) {
            int t = __shfl_up(a, d, 64);
            if (lane >= d) a += t;
        }
        if (tid == 63) w0s = a;
        __syncthreads();
        if (tid < 128) {
            int incl = a + (tid >= 64 ? w0s : 0);
            cnt[k * 128 + tid] = incl - v;     // exclusive prefix over blocks
            if (tid == 127) bHist[k] = incl;   // bucket total
        }
        return;
    }

    // ---- convert part ----
    int i = blockIdx.x * 256 + threadIdx.x;
    if (i < nx4) {                         // x: float4 -> ushort4 (bf16)
        float4 v = ((const float4*)x)[i];
        ushort4 o;
        o.x = f2b(v.x); o.y = f2b(v.y); o.z = f2b(v.z); o.w = f2b(v.w);
        ((ushort4*)xb)[i] = o;
        return;
    }
    i -= nx4;
    if (i < FDIM * FDIM) {                 // W1: [256][256] -> [c][r]
        int r = i >> 8, c = i & 255;
        Wt1[c * FDIM + r] = f2b(W1[i]);
        return;
    }
    i -= FDIM * FDIM;
    if (i < FDIM * FDIM) {
        int r = i >> 8, c = i & 255;
        Wt2[c * FDIM + r] = f2b(W2[i]);
        return;
    }
    i -= FDIM * FDIM;
    if (i < FDIM * 64) {                   // fcW: [256][64] -> [c][r]
        int r = i >> 6, c = i & 63;
        fcWt[c * FDIM + r] = f2b(fcW[i]);
    }
}

// ---------------------------------------------------------------------------
// Exclusive scan of bucket totals -> bOffs[0..nbk]. One wave, 32 elems/lane.
// ---------------------------------------------------------------------------
__global__ void bscan(const int* __restrict__ bHist, int* __restrict__ bOffs,
                      int nbk) {
    const int tid = threadIdx.x;           // 0..63
    const int base = tid * 32;
    int vals[32];
    int s = 0;
#pragma unroll
    for (int k = 0; k < 32; ++k) {
        int idx = base + k;
        int v = (idx < nbk) ? bHist[idx] : 0;
        vals[k] = s;
        s += v;
    }
    int acc = s;
#pragma unroll
    for (int d = 1; d < 64; d <<= 1) {
        int t = __shfl_up(acc, d, 64);
        if (tid >= d) acc += t;
    }
    const int pre = acc - s;
#pragma unroll
    for (int k = 0; k < 32; ++k) {
        int idx = base + k;
        if (idx <= nbk) bOffs[idx] = pre + vals[k];
    }
}

// ---------------------------------------------------------------------------
// Pass 2: scatter edges into bucket-sorted pairs with LDS cursors seeded
// from bOffs[k] + cnt[k][b]. Plain global writes, ZERO global atomics.
// Grid/stride must match cnt_hist exactly.
// ---------------------------------------------------------------------------
__global__ void bscatter(const int* __restrict__ srcp, const int* __restrict__ dstp,
                         const int* __restrict__ bOffs, const int* __restrict__ cnt,
                         unsigned int* __restrict__ pairs,
                         int E, int Et, int nbk) {
    __shared__ int lcur[NBK_MAX];
    const int tid = threadIdx.x, b = blockIdx.x;
    for (int k = tid; k < nbk; k += 1024) lcur[k] = bOffs[k] + cnt[k * 128 + b];
    __syncthreads();
    for (int e = b * 1024 + tid; e < Et; e += 131072) {
        int s, dd;
        if (e < E) { s = srcp[e]; dd = dstp[e]; }
        else       { s = e - E;   dd = s; }
        int pos = atomicAdd(&lcur[dd >> 5], 1);
        pairs[pos] = (unsigned)s | ((unsigned)(dd & 31) << 16);
    }
}

// ---------------------------------------------------------------------------
// Per-bucket CSR build: bucket b covers nodes [b*32, b*32+32), edges in
// pairs[bOffs[b] .. bOffs[b+1]). LDS hist -> scan -> LDS-cursor scatter.
// ---------------------------------------------------------------------------
__global__ void csr_build(const unsigned int* __restrict__ pairs,
                          const int* __restrict__ bOffs,
                          int* __restrict__ offs, int* __restrict__ deg,
                          int* __restrict__ csr_src, int n) {
    __shared__ int hist[32], loc[32], lcur[32];
    const int b = blockIdx.x;
    const int tid = threadIdx.x;
    const int rb = bOffs[b], re = bOffs[b + 1];

    if (tid < 32) hist[tid] = 0;
    __syncthreads();
    for (int i = rb + tid; i < re; i += 128) {
        unsigned p = pairs[i];
        atomicAdd(&hist[(p >> 16) & 31], 1);
    }
    __syncthreads();
    if (tid < 32) {
        int v = hist[tid];
        int a = v;
#pragma unroll
        for (int d = 1; d < 32; d <<= 1) {
            int t = __shfl_up(a, d, 32);
            if (tid >= d) a += t;
        }
        int lo = a - v;                   // exclusive local offset
        loc[tid] = lo;
        lcur[tid] = 0;
        int node = b * 32 + tid;
        if (node < n) {
            offs[node] = rb + lo;
            deg[node] = v;
        }
    }
    __syncthreads();
    for (int i = rb + tid; i < re; i += 128) {
        unsigned p = pairs[i];
        int dl = (p >> 16) & 31;
        int pos = atomicAdd(&lcur[dl], 1);
        csr_src[rb + loc[dl] + pos] = (int)(p & 0xFFFFu);
    }
}

// ---------------------------------------------------------------------------
// GEMM, LDS-free: C[M][ncol] = A[M][256](bf16) x Bt[ncol][256]^T(bf16).
// Each lane loads its MFMA fragments (16B aligned) directly from global:
// K=256 is 4 unrolled steps of {16 loads + 32 MFMA}, no barriers, no LDS.
// B (<=128KB) is L2-resident; A streamed once (each row's 16 chunks are
// fully consumed by one wave -> every fetched line fully used).
// 1-D grid, m204 bijective XCD-chunk swizzle (A-panel pair shares L2).
// ATT: fused attention-coefficient epilogue, pre-scaled by log2(e) so the
// gather kernel uses a bare v_exp_f32 (exp2); exact (leaky_relu is
// positively homogeneous). C-write: direct stores (R19 form).
// ---------------------------------------------------------------------------
template <int BN, bool F32OUT, bool ATT>
__global__ __launch_bounds__(256, 2)
void gemm_bt_k256(const unsigned short* __restrict__ A,
                  const unsigned short* __restrict__ Bt,
                  void* __restrict__ C,
                  const float* __restrict__ bias,
                  const float* __restrict__ a_src,
                  const float* __restrict__ a_dst,
                  float* __restrict__ als,
                  float* __restrict__ ald,
                  int M, int ncol) {
    constexpr int BM = 128;
    constexpr int NFRAG = BN / 32;
    constexpr int YNUM = (BN == 128) ? 2 : 1;

    const int mb = (M + 127) >> 7;
    const int nwg = mb * YNUM;
    int bid = blockIdx.x;

    // m204 bijective XCD-chunk swizzle (8 XCDs)
    {
        const int q = nwg >> 3, r = nwg & 7;
        const int xcd = bid & 7, sub = bid >> 3;
        bid = (xcd < r ? xcd * (q + 1) : r * (q + 1) + (xcd - r) * q) + sub;
    }
    const int gy = (YNUM == 2) ? (bid & 1) : 0;
    const int gx = (YNUM == 2) ? (bid >> 1) : bid;

    const int tid  = threadIdx.x;
    const int lane = tid & 63;
    const int wave = tid >> 6;
    const int wm = wave & 1, wn = wave >> 1;
    const int m0 = gx * BM;
    const int n0 = gy * BN;
    const int quad = lane >> 4, col16 = lane & 15;

    // per-lane fragment row offsets (elements)
    int arow[4];
#pragma unroll
    for (int i = 0; i < 4; ++i) {
        int r = m0 + wm * 64 + i * 16 + col16;
        r = r < M ? r : (M - 1);
        arow[i] = r * FDIM;
    }
    int bcol[NFRAG];
#pragma unroll
    for (int j = 0; j < NFRAG; ++j)
        bcol[j] = (n0 + wn * (BN / 2) + j * 16 + col16) * FDIM;

    f32x4 acc[4][NFRAG];
#pragma unroll
    for (int i = 0; i < 4; ++i)
#pragma unroll
        for (int j = 0; j < NFRAG; ++j) acc[i][j] = (f32x4){0.f, 0.f, 0.f, 0.f};

#pragma unroll 1
    for (int kt = 0; kt < 4; ++kt) {
        const int kq = kt * 64 + quad * 8;
#pragma unroll
        for (int kk = 0; kk < 2; ++kk) {
            const int ko = kq + kk * 32;            // k element offset
            s16x8 af[4], bfr[NFRAG];
#pragma unroll
            for (int i = 0; i < 4; ++i)
                af[i] = *(const s16x8*)(A + arow[i] + ko);
#pragma unroll
            for (int j = 0; j < NFRAG; ++j)
                bfr[j] = *(const s16x8*)(Bt + bcol[j] + ko);
#pragma unroll
            for (int i = 0; i < 4; ++i)
#pragma unroll
                for (int j = 0; j < NFRAG; ++j)
                    acc[i][j] = __builtin_amdgcn_mfma_f32_16x16x32_bf16(
                        af[i], bfr[j], acc[i][j], 0, 0, 0);
        }
    }

    // C epilogue: D row = quad*4 + r, col = lane&15 (m89-verified layout)
#pragma unroll
    for (int i = 0; i < 4; ++i) {
#pragma unroll
        for (int j = 0; j < NFRAG; ++j) {
#pragma unroll
            for (int r = 0; r < 4; ++r) {
                int row = m0 + wm * 64 + i * 16 + quad * 4 + r;
                int col = n0 + wn * (BN / 2) + j * 16 + col16;
                if (row < M) {
                    float v = acc[i][j][r];
                    if (bias) v += bias[col];
                    if constexpr (F32OUT)
                        ((float*)C)[(size_t)row * ncol + col] = v;
                    else
                        ((unsigned short*)C)[(size_t)row * ncol + col] = f2b(v);
                }
            }
        }
    }

    if constexpr (ATT) {
        constexpr float LOG2E = 1.4426950408889634f;
        const int head = gy * 2 + wn;
        float asv[4], adv[4];
#pragma unroll
        for (int j = 0; j < 4; ++j) {
            int c = head * 64 + j * 16 + col16;
            asv[j] = a_src[c] * LOG2E;
            adv[j] = a_dst[c] * LOG2E;
        }
#pragma unroll
        for (int i = 0; i < 4; ++i) {
#pragma unroll
            for (int r = 0; r < 4; ++r) {
                float vs = acc[i][0][r] * asv[0] + acc[i][1][r] * asv[1]
                         + acc[i][2][r] * asv[2] + acc[i][3][r] * asv[3];
                float vd = acc[i][0][r] * adv[0] + acc[i][1][r] * adv[1]
                         + acc[i][2][r] * adv[2] + acc[i][3][r] * adv[3];
#pragma unroll
                for (int m = 1; m < 16; m <<= 1) {
                    vs += __shfl_xor(vs, m, 16);
                    vd += __shfl_xor(vd, m, 16);
                }
                int row = m0 + wm * 64 + i * 16 + quad * 4 + r;
                if (col16 == 0 && row < M) {
                    als[row * HEADS + head] = vs;
                    ald[row * HEADS + head] = vd;
                }
            }
        }
    }
}

// ---------------------------------------------------------------------------
// Fused gather (R11 form: one wave per dst node, 4 ch/lane, 8x unroll; 8
// rows of h in flight). als/ald arrive pre-scaled by log2(e) -> bare exp2.
// ---------------------------------------------------------------------------
__global__ void gat_gather(const int* __restrict__ off,
                           const int* __restrict__ deg,
                           const int* __restrict__ csr_src,
                           const float* __restrict__ als,
                           const float* __restrict__ ald,
                           const unsigned short* __restrict__ h,
                           const float* __restrict__ bias,
                           unsigned short* __restrict__ x2, int n) {
    const int lane = threadIdx.x & 63;
    const int d = (blockIdx.x * blockDim.x + threadIdx.x) >> 6;
    if (d >= n) return;
    const int head = lane >> 4;
    const float aldh = ald[4 * d + head];
    const int start = off[d];
    const int end = start + deg[d];

    float a0 = 0.f, a1 = 0.f, a2 = 0.f, a3 = 0.f, den = 0.f;
    int j = start;
    for (; j + 8 <= end; j += 8) {
        int s[8];
#pragma unroll
        for (int u = 0; u < 8; ++u) s[u] = csr_src[j + u];
        float e[8];
#pragma unroll
        for (int u = 0; u < 8; ++u) e[u] = als[4 * s[u] + head];
        ushort4 hv[8];
#pragma unroll
        for (int u = 0; u < 8; ++u)
            hv[u] = *(const ushort4*)(h + (size_t)s[u] * FDIM + lane * 4);
#pragma unroll
        for (int u = 0; u < 8; ++u) {
            float t = e[u] + aldh;
            t = t > 0.f ? t : 0.2f * t;
            float w = fast_exp2(t);
            den += w;
            a0 += w * b2f(hv[u].x);
            a1 += w * b2f(hv[u].y);
            a2 += w * b2f(hv[u].z);
            a3 += w * b2f(hv[u].w);
        }
    }
    for (; j + 4 <= end; j += 4) {
        int s[4];
#pragma unroll
        for (int u = 0; u < 4; ++u) s[u] = csr_src[j + u];
        float e[4];
#pragma unroll
        for (int u = 0; u < 4; ++u) e[u] = als[4 * s[u] + head];
        ushort4 hv[4];
#pragma unroll
        for (int u = 0; u < 4; ++u)
            hv[u] = *(const ushort4*)(h + (size_t)s[u] * FDIM + lane * 4);
#pragma unroll
        for (int u = 0; u < 4; ++u) {
            float t = e[u] + aldh;
            t = t > 0.f ? t : 0.2f * t;
            float w = fast_exp2(t);
            den += w;
            a0 += w * b2f(hv[u].x);
            a1 += w * b2f(hv[u].y);
            a2 += w * b2f(hv[u].z);
            a3 += w * b2f(hv[u].w);
        }
    }
    for (; j < end; ++j) {
        int s = csr_src[j];
        float t = als[4 * s + head] + aldh;
        t = t > 0.f ? t : 0.2f * t;
        float w = fast_exp2(t);
        ushort4 hv = *(const ushort4*)(h + (size_t)s * FDIM + lane * 4);
        den += w;
        a0 += w * b2f(hv.x);
        a1 += w * b2f(hv.y);
        a2 += w * b2f(hv.z);
        a3 += w * b2f(hv.w);
    }
    const float inv = 1.0f / den;
    const int c = lane * 4;
    float v0 = a0 * inv + bias[c + 0];
    float v1 = a1 * inv + bias[c + 1];
    float v2 = a2 * inv + bias[c + 2];
    float v3 = a3 * inv + bias[c + 3];
    v0 = v0 > 0.f ? v0 : expm1f(v0);
    v1 = v1 > 0.f ? v1 : expm1f(v1);
    v2 = v2 > 0.f ? v2 : expm1f(v2);
    v3 = v3 > 0.f ? v3 : expm1f(v3);
    ushort4 o;
    o.x = f2b(v0); o.y = f2b(v1); o.z = f2b(v2); o.w = f2b(v3);
    *(ushort4*)(x2 + (size_t)d * FDIM + c) = o;
}

// ---------------------------------------------------------------------------
extern "C" void kernel_launch(void* const* d_in, const int* in_sizes, int n_in,
                              void* d_out, int out_size, void* d_ws, size_t ws_size,
                              hipStream_t stream) {
    const float* x   = (const float*)d_in[0];
    const int*   ei  = (const int*)d_in[1];
    const float* W1  = (const float*)d_in[3];
    const float* as1 = (const float*)d_in[4];
    const float* ad1 = (const float*)d_in[5];
    const float* b1  = (const float*)d_in[6];
    const float* W2  = (const float*)d_in[7];
    const float* as2 = (const float*)d_in[8];
    const float* ad2 = (const float*)d_in[9];
    const float* b2  = (const float*)d_in[10];
    const float* fcW = (const float*)d_in[11];
    const float* fcb = (const float*)d_in[12];
    float* out = (float*)d_out;

    const int n = in_sizes[0] / FDIM;   // 50000
    const int E = in_sizes[1] / 2;      // 800000
    const int Etot = E + n;
    const int* srcp = ei;
    const int* dstp = ei + E;
    const int nbk = (n + 31) / 32;      // 1563 buckets

    // -------- workspace carve (256B aligned), ~62 MB --------
    char* ws = (char*)d_ws;
    size_t off_b = 0;
    auto carve = [&](size_t bytes) -> char* {
        char* p = ws + off_b;
        off_b += (bytes + 255) & ~(size_t)255;
        return p;
    };
    unsigned short* xb = (unsigned short*)carve((size_t)n * FDIM * 2);  // also x2
    unsigned short* h  = (unsigned short*)carve((size_t)n * FDIM * 2);
    float* als  = (float*)carve((size_t)n * HEADS * 4);
    float* ald  = (float*)carve((size_t)n * HEADS * 4);
    int* deg    = (int*)carve((size_t)n * 4);
    int* offs   = (int*)carve((size_t)(n + 1) * 4);
    int* cnt    = (int*)carve((size_t)NBK_MAX * 128 * 4);   // 1 MB, k-major
    int* bHist  = (int*)carve((size_t)NBK_MAX * 4);
    int* bOffs  = (int*)carve((size_t)(NBK_MAX + 1) * 4);
    unsigned int* pairs = (unsigned int*)carve((size_t)Etot * 4);
    int* csr_src = (int*)carve((size_t)Etot * 4);
    unsigned short* Wt1  = (unsigned short*)carve(FDIM * FDIM * 2);
    unsigned short* Wt2  = (unsigned short*)carve(FDIM * FDIM * 2);
    unsigned short* fcWt = (unsigned short*)carve(64 * FDIM * 2);
    unsigned short* x2 = xb;   // alias: xb dead after layer-1 GEMM

    const int mblocks = (n + 127) / 128;
    const int nx4 = n * FDIM / 4;
    const int cvtblocks = (nx4 + 2 * FDIM * FDIM + FDIM * 64 + 255) / 256;

    // -------- CSR build (atomic-free counting sort) --------
    cnt_hist<<<128, 1024, 0, stream>>>(dstp, cnt, E, Etot, nbk);
    cvt_scan<<<cvtblocks + nbk, 256, 0, stream>>>(
        x, xb, W1, Wt1, W2, Wt2, fcW, fcWt, cnt, bHist, nx4, cvtblocks);
    bscan<<<1, 64, 0, stream>>>(bHist, bOffs, nbk);
    bscatter<<<128, 1024, 0, stream>>>(srcp, dstp, bOffs, cnt, pairs, E, Etot, nbk);
    csr_build<<<nbk, 128, 0, stream>>>(pairs, bOffs, offs, deg, csr_src, n);

    // -------- layer 1 --------
    gemm_bt_k256<128, false, true><<<mblocks * 2, 256, 0, stream>>>(
        xb, Wt1, h, nullptr, as1, ad1, als, ald, n, FDIM);
    gat_gather<<<(n + 3) / 4, 256, 0, stream>>>(
        offs, deg, csr_src, als, ald, h, b1, x2, n);

    // -------- layer 2 --------
    gemm_bt_k256<128, false, true><<<mblocks * 2, 256, 0, stream>>>(
        x2, Wt2, h, nullptr, as2, ad2, als, ald, n, FDIM);
    gat_gather<<<(n + 3) / 4, 256, 0, stream>>>(
        offs, deg, csr_src, als, ald, h, b2, x2, n);

    // -------- final FC: out[n][64] = x2 @ fcW + fcb (FP32 out) --------
    gemm_bt_k256<64, true, false><<<mblocks, 256, 0, stream>>>(
        x2, fcWt, out, fcb, nullptr, nullptr, nullptr, nullptr, n, 64);
}

// Round 12
// 323.635 us; speedup vs baseline: 1.1538x; 1.1538x over previous
//
#include <hip/hip_runtime.h>
#include <hip/hip_bf16.h>

// ---------------------------------------------------------------------------
// NextTaskGAT: 2-layer GAT (H=4, C=64, F_IN=256) + FC(256->64).
// Pinned: inputs fp32 (bf16-grid), edge_index int32, dict order, OUTPUT FP32.
// R23 = R19 (best, 324.3) with the GEMM grid-limit fixed: occupancy was 36%
// == 782 blocks / 256 CU (grid-limited, not VGPR/LDS). BM 128->64 doubles
// the grid (1564 blocks, 6/CU, 24KB LDS) so resident waves hide the 4x
// {stage -> vmcnt(0) -> barrier} chains. K-loop = R19 staged form (R22's
// LDS-free variant was 16-way-scattered loads, -49us; reverted).
// CSR = R19 atomic-free counting sort; gather = R11 form; exp2-folded att.
// ---------------------------------------------------------------------------

#define HEADS 4
#define FDIM  256
#define NBK_MAX 2048   // max buckets (n <= 65536); bucket = dst>>5

typedef __attribute__((ext_vector_type(4))) float f32x4;
typedef __attribute__((ext_vector_type(8))) short s16x8;

__device__ __forceinline__ void gload_lds16(const void* g, void* l) {
    __builtin_amdgcn_global_load_lds(
        (__attribute__((address_space(1))) void*)g,
        (__attribute__((address_space(3))) void*)l, 16, 0, 0);
}

__device__ __forceinline__ float b2f(unsigned short u) {
    return __uint_as_float((unsigned)u << 16);
}
__device__ __forceinline__ unsigned short f2b(float f) {
    __hip_bfloat16 b = __float2bfloat16(f);
    return *(unsigned short*)&b;
}

__device__ __forceinline__ float fast_exp2(float t) {
#if __has_builtin(__builtin_amdgcn_exp2f)
    return __builtin_amdgcn_exp2f(t);
#else
    return __expf(t * 0.6931471805599453f);
#endif
}

// ---------------------------------------------------------------------------
// Pass 1: per-block bucket histogram (LDS atomics only).
// cnt layout k-major: cnt[k*128 + b]. Grid MUST be <<<128,1024>>> and the
// grid-stride loop must match bscatter exactly (same block -> same edges).
// ---------------------------------------------------------------------------
__global__ void cnt_hist(const int* __restrict__ dstp, int* __restrict__ cnt,
                         int E, int Et, int nbk) {
    __shared__ int lh[NBK_MAX];
    const int tid = threadIdx.x, b = blockIdx.x;
    for (int i = tid; i < NBK_MAX; i += 1024) lh[i] = 0;
    __syncthreads();
    for (int e = b * 1024 + tid; e < Et; e += 131072) {
        int dd = (e < E) ? dstp[e] : (e - E);
        atomicAdd(&lh[dd >> 5], 1);
    }
    __syncthreads();
    for (int k = tid; k < nbk; k += 1024) cnt[k * 128 + b] = lh[k];
}

// ---------------------------------------------------------------------------
// Fused conversions + per-bucket column scan in ONE dispatch.
// Blocks [0, cvtblocks): x->bf16 (x4 vec) | W1^T | W2^T | fcW^T.
// Blocks [cvtblocks, cvtblocks+nbk): block k scans cnt[k][0..127] ->
// in-place exclusive per-block prefix; total -> bHist[k].
// ---------------------------------------------------------------------------
__global__ void cvt_scan(const float* __restrict__ x, unsigned short* __restrict__ xb,
                         const float* __restrict__ W1, unsigned short* __restrict__ Wt1,
                         const float* __restrict__ W2, unsigned short* __restrict__ Wt2,
                         const float* __restrict__ fcW, unsigned short* __restrict__ fcWt,
                         int* __restrict__ cnt, int* __restrict__ bHist,
                         int nx4, int cvtblocks) {
    if ((int)blockIdx.x >= cvtblocks) {
        const int k = (int)blockIdx.x - cvtblocks;
        const int tid = threadIdx.x;
        __shared__ int w0s;
        int v = 0;
        if (tid < 128) v = cnt[k * 128 + tid];
        const int lane = tid & 63;
        int a = v;
#pragma unroll
        for (int d = 1; d < 64; d <<= 1) {
            int t = __shfl_up(a, d, 64);
            if (lane >= d) a += t;
        }
        if (tid == 63) w0s = a;
        __syncthreads();
        if (tid < 128) {
            int incl = a + (tid >= 64 ? w0s : 0);
            cnt[k * 128 + tid] = incl - v;     // exclusive prefix over blocks
            if (tid == 127) bHist[k] = incl;   // bucket total
        }
        return;
    }

    // ---- convert part ----
    int i = blockIdx.x * 256 + threadIdx.x;
    if (i < nx4) {                         // x: float4 -> ushort4 (bf16)
        float4 v = ((const float4*)x)[i];
        ushort4 o;
        o.x = f2b(v.x); o.y = f2b(v.y); o.z = f2b(v.z); o.w = f2b(v.w);
        ((ushort4*)xb)[i] = o;
        return;
    }
    i -= nx4;
    if (i < FDIM * FDIM) {                 // W1: [256][256] -> [c][r]
        int r = i >> 8, c = i & 255;
        Wt1[c * FDIM + r] = f2b(W1[i]);
        return;
    }
    i -= FDIM * FDIM;
    if (i < FDIM * FDIM) {
        int r = i >> 8, c = i & 255;
        Wt2[c * FDIM + r] = f2b(W2[i]);
        return;
    }
    i -= FDIM * FDIM;
    if (i < FDIM * 64) {                   // fcW: [256][64] -> [c][r]
        int r = i >> 6, c = i & 63;
        fcWt[c * FDIM + r] = f2b(fcW[i]);
    }
}

// ---------------------------------------------------------------------------
// Exclusive scan of bucket totals -> bOffs[0..nbk]. One wave, 32 elems/lane.
// ---------------------------------------------------------------------------
__global__ void bscan(const int* __restrict__ bHist, int* __restrict__ bOffs,
                      int nbk) {
    const int tid = threadIdx.x;           // 0..63
    const int base = tid * 32;
    int vals[32];
    int s = 0;
#pragma unroll
    for (int k = 0; k < 32; ++k) {
        int idx = base + k;
        int v = (idx < nbk) ? bHist[idx] : 0;
        vals[k] = s;
        s += v;
    }
    int acc = s;
#pragma unroll
    for (int d = 1; d < 64; d <<= 1) {
        int t = __shfl_up(acc, d, 64);
        if (tid >= d) acc += t;
    }
    const int pre = acc - s;
#pragma unroll
    for (int k = 0; k < 32; ++k) {
        int idx = base + k;
        if (idx <= nbk) bOffs[idx] = pre + vals[k];
    }
}

// ---------------------------------------------------------------------------
// Pass 2: scatter edges into bucket-sorted pairs with LDS cursors seeded
// from bOffs[k] + cnt[k][b]. Plain global writes, ZERO global atomics.
// Grid/stride must match cnt_hist exactly.
// ---------------------------------------------------------------------------
__global__ void bscatter(const int* __restrict__ srcp, const int* __restrict__ dstp,
                         const int* __restrict__ bOffs, const int* __restrict__ cnt,
                         unsigned int* __restrict__ pairs,
                         int E, int Et, int nbk) {
    __shared__ int lcur[NBK_MAX];
    const int tid = threadIdx.x, b = blockIdx.x;
    for (int k = tid; k < nbk; k += 1024) lcur[k] = bOffs[k] + cnt[k * 128 + b];
    __syncthreads();
    for (int e = b * 1024 + tid; e < Et; e += 131072) {
        int s, dd;
        if (e < E) { s = srcp[e]; dd = dstp[e]; }
        else       { s = e - E;   dd = s; }
        int pos = atomicAdd(&lcur[dd >> 5], 1);
        pairs[pos] = (unsigned)s | ((unsigned)(dd & 31) << 16);
    }
}

// ---------------------------------------------------------------------------
// Per-bucket CSR build: bucket b covers nodes [b*32, b*32+32), edges in
// pairs[bOffs[b] .. bOffs[b+1]). LDS hist -> scan -> LDS-cursor scatter.
// ---------------------------------------------------------------------------
__global__ void csr_build(const unsigned int* __restrict__ pairs,
                          const int* __restrict__ bOffs,
                          int* __restrict__ offs, int* __restrict__ deg,
                          int* __restrict__ csr_src, int n) {
    __shared__ int hist[32], loc[32], lcur[32];
    const int b = blockIdx.x;
    const int tid = threadIdx.x;
    const int rb = bOffs[b], re = bOffs[b + 1];

    if (tid < 32) hist[tid] = 0;
    __syncthreads();
    for (int i = rb + tid; i < re; i += 128) {
        unsigned p = pairs[i];
        atomicAdd(&hist[(p >> 16) & 31], 1);
    }
    __syncthreads();
    if (tid < 32) {
        int v = hist[tid];
        int a = v;
#pragma unroll
        for (int d = 1; d < 32; d <<= 1) {
            int t = __shfl_up(a, d, 32);
            if (tid >= d) a += t;
        }
        int lo = a - v;                   // exclusive local offset
        loc[tid] = lo;
        lcur[tid] = 0;
        int node = b * 32 + tid;
        if (node < n) {
            offs[node] = rb + lo;
            deg[node] = v;
        }
    }
    __syncthreads();
    for (int i = rb + tid; i < re; i += 128) {
        unsigned p = pairs[i];
        int dl = (p >> 16) & 31;
        int pos = atomicAdd(&lcur[dl], 1);
        csr_src[rb + loc[dl] + pos] = (int)(p & 0xFFFFu);
    }
}

// ---------------------------------------------------------------------------
// GEMM: C[M][ncol] = A[M][256](bf16) x Bt[ncol][256]^T(bf16), +fp32 bias.
// Template BM/BN. 4 waves 2x2 (wm rows, wn cols); MFRAG=BM/32 row-frags,
// NFRAG=BN/32 col-frags per wave. XOR-swizzled 16B groups, global_load_lds,
// single-buffer K-loop (R14 form, measured best at K=256).
// BM=64: 1564 blocks (6/CU, 24KB LDS) -> occupancy ~75% vs BM=128's
// grid-limited 36% -- resident waves hide the per-block stage/drain chains.
// 1-D grid, m204 bijective XCD-chunk swizzle.
// ATT: fused attention-coefficient epilogue, pre-scaled by log2(e) so the
// gather kernel uses a bare v_exp_f32 (exp2); exact (leaky_relu is
// positively homogeneous). head = gy*2+wn requires BN=128.
// ---------------------------------------------------------------------------
template <int BM, int BN, bool F32OUT, bool ATT>
__global__ __launch_bounds__(256, 2)
void gemm_bt_k256(const unsigned short* __restrict__ A,
                  const unsigned short* __restrict__ Bt,
                  void* __restrict__ C,
                  const float* __restrict__ bias,
                  const float* __restrict__ a_src,
                  const float* __restrict__ a_dst,
                  float* __restrict__ als,
                  float* __restrict__ ald,
                  int M, int ncol) {
    constexpr int BK = 64;
    constexpr int MFRAG = BM / 32;
    constexpr int NFRAG = BN / 32;
    constexpr int YNUM = (BN == 128) ? 2 : 1;
    __shared__ __align__(16) unsigned short lA[BM * BK];
    __shared__ __align__(16) unsigned short lB[BN * BK];

    const int mb = (M + BM - 1) / BM;
    const int nwg = mb * YNUM;
    int bid = blockIdx.x;

    // m204 bijective XCD-chunk swizzle (8 XCDs)
    {
        const int q = nwg >> 3, r = nwg & 7;
        const int xcd = bid & 7, sub = bid >> 3;
        bid = (xcd < r ? xcd * (q + 1) : r * (q + 1) + (xcd - r) * q) + sub;
    }
    const int gy = (YNUM == 2) ? (bid & 1) : 0;
    const int gx = (YNUM == 2) ? (bid >> 1) : bid;

    const int tid  = threadIdx.x;
    const int lane = tid & 63;
    const int wave = tid >> 6;
    const int wm = wave & 1, wn = wave >> 1;
    const int m0 = gx * BM;
    const int n0 = gy * BN;
    const int quad = lane >> 4, col16 = lane & 15;

    f32x4 acc[MFRAG][NFRAG];
#pragma unroll
    for (int i = 0; i < MFRAG; ++i)
#pragma unroll
        for (int j = 0; j < NFRAG; ++j) acc[i][j] = (f32x4){0.f, 0.f, 0.f, 0.f};

#pragma unroll 1
    for (int kt = 0; kt < 4; ++kt) {
        const int k0 = kt * BK;
#pragma unroll
        for (int i = 0; i < BM / 32; ++i) {          // A: BM*8 granules
            int slot = tid + i * 256;
            int row = slot >> 3, g = slot & 7;
            int gs = g ^ (row & 7);
            int rg = m0 + row; rg = rg < M ? rg : (M - 1);
            gload_lds16(A + (size_t)rg * FDIM + k0 + gs * 8,
                        (char*)lA + (size_t)slot * 16);
        }
#pragma unroll
        for (int i = 0; i < BN / 32; ++i) {          // B: BN*8 granules
            int slot = tid + i * 256;
            int row = slot >> 3, g = slot & 7;
            int gs = g ^ (row & 7);
            gload_lds16(Bt + (size_t)(n0 + row) * FDIM + k0 + gs * 8,
                        (char*)lB + (size_t)slot * 16);
        }
        __syncthreads();

#pragma unroll
        for (int kk = 0; kk < 2; ++kk) {
            const int kg = kk * 4 + quad;
            s16x8 af[MFRAG], bfr[NFRAG];
#pragma unroll
            for (int i = 0; i < MFRAG; ++i) {
                int row = wm * (BM / 2) + i * 16 + col16;
                int g = kg ^ (row & 7);
                af[i] = *(const s16x8*)((const char*)lA + (size_t)(row * 8 + g) * 16);
            }
#pragma unroll
            for (int j = 0; j < NFRAG; ++j) {
                int row = wn * (BN / 2) + j * 16 + col16;
                int g = kg ^ (row & 7);
                bfr[j] = *(const s16x8*)((const char*)lB + (size_t)(row * 8 + g) * 16);
            }
#pragma unroll
            for (int i = 0; i < MFRAG; ++i)
#pragma unroll
                for (int j = 0; j < NFRAG; ++j)
                    acc[i][j] = __builtin_amdgcn_mfma_f32_16x16x32_bf16(
                        af[i], bfr[j], acc[i][j], 0, 0, 0);
        }
        __syncthreads();
    }

    // C epilogue: D row = quad*4 + r, col = lane&15 (m89-verified layout)
#pragma unroll
    for (int i = 0; i < MFRAG; ++i) {
#pragma unroll
        for (int j = 0; j < NFRAG; ++j) {
#pragma unroll
            for (int r = 0; r < 4; ++r) {
                int row = m0 + wm * (BM / 2) + i * 16 + quad * 4 + r;
                int col = n0 + wn * (BN / 2) + j * 16 + col16;
                if (row < M) {
                    float v = acc[i][j][r];
                    if (bias) v += bias[col];
                    if constexpr (F32OUT)
                        ((float*)C)[(size_t)row * ncol + col] = v;
                    else
                        ((unsigned short*)C)[(size_t)row * ncol + col] = f2b(v);
                }
            }
        }
    }

    if constexpr (ATT) {
        constexpr float LOG2E = 1.4426950408889634f;
        const int head = gy * 2 + wn;
        float asv[4], adv[4];
#pragma unroll
        for (int j = 0; j < 4; ++j) {
            int c = head * 64 + j * 16 + col16;
            asv[j] = a_src[c] * LOG2E;
            adv[j] = a_dst[c] * LOG2E;
        }
#pragma unroll
        for (int i = 0; i < MFRAG; ++i) {
#pragma unroll
            for (int r = 0; r < 4; ++r) {
                float vs = acc[i][0][r] * asv[0] + acc[i][1][r] * asv[1]
                         + acc[i][2][r] * asv[2] + acc[i][3][r] * asv[3];
                float vd = acc[i][0][r] * adv[0] + acc[i][1][r] * adv[1]
                         + acc[i][2][r] * adv[2] + acc[i][3][r] * adv[3];
#pragma unroll
                for (int m = 1; m < 16; m <<= 1) {
                    vs += __shfl_xor(vs, m, 16);
                    vd += __shfl_xor(vd, m, 16);
                }
                int row = m0 + wm * (BM / 2) + i * 16 + quad * 4 + r;
                if (col16 == 0 && row < M) {
                    als[row * HEADS + head] = vs;
                    ald[row * HEADS + head] = vd;
                }
            }
        }
    }
}

// ---------------------------------------------------------------------------
// Fused gather (R11 form: one wave per dst node, 4 ch/lane, 8x unroll; 8
// rows of h in flight). als/ald arrive pre-scaled by log2(e) -> bare exp2.
// ---------------------------------------------------------------------------
__global__ void gat_gather(const int* __restrict__ off,
                           const int* __restrict__ deg,
                           const int* __restrict__ csr_src,
                           const float* __restrict__ als,
                           const float* __restrict__ ald,
                           const unsigned short* __restrict__ h,
                           const float* __restrict__ bias,
                           unsigned short* __restrict__ x2, int n) {
    const int lane = threadIdx.x & 63;
    const int d = (blockIdx.x * blockDim.x + threadIdx.x) >> 6;
    if (d >= n) return;
    const int head = lane >> 4;
    const float aldh = ald[4 * d + head];
    const int start = off[d];
    const int end = start + deg[d];

    float a0 = 0.f, a1 = 0.f, a2 = 0.f, a3 = 0.f, den = 0.f;
    int j = start;
    for (; j + 8 <= end; j += 8) {
        int s[8];
#pragma unroll
        for (int u = 0; u < 8; ++u) s[u] = csr_src[j + u];
        float e[8];
#pragma unroll
        for (int u = 0; u < 8; ++u) e[u] = als[4 * s[u] + head];
        ushort4 hv[8];
#pragma unroll
        for (int u = 0; u < 8; ++u)
            hv[u] = *(const ushort4*)(h + (size_t)s[u] * FDIM + lane * 4);
#pragma unroll
        for (int u = 0; u < 8; ++u) {
            float t = e[u] + aldh;
            t = t > 0.f ? t : 0.2f * t;
            float w = fast_exp2(t);
            den += w;
            a0 += w * b2f(hv[u].x);
            a1 += w * b2f(hv[u].y);
            a2 += w * b2f(hv[u].z);
            a3 += w * b2f(hv[u].w);
        }
    }
    for (; j + 4 <= end; j += 4) {
        int s[4];
#pragma unroll
        for (int u = 0; u < 4; ++u) s[u] = csr_src[j + u];
        float e[4];
#pragma unroll
        for (int u = 0; u < 4; ++u) e[u] = als[4 * s[u] + head];
        ushort4 hv[4];
#pragma unroll
        for (int u = 0; u < 4; ++u)
            hv[u] = *(const ushort4*)(h + (size_t)s[u] * FDIM + lane * 4);
#pragma unroll
        for (int u = 0; u < 4; ++u) {
            float t = e[u] + aldh;
            t = t > 0.f ? t : 0.2f * t;
            float w = fast_exp2(t);
            den += w;
            a0 += w * b2f(hv[u].x);
            a1 += w * b2f(hv[u].y);
            a2 += w * b2f(hv[u].z);
            a3 += w * b2f(hv[u].w);
        }
    }
    for (; j < end; ++j) {
        int s = csr_src[j];
        float t = als[4 * s + head] + aldh;
        t = t > 0.f ? t : 0.2f * t;
        float w = fast_exp2(t);
        ushort4 hv = *(const ushort4*)(h + (size_t)s * FDIM + lane * 4);
        den += w;
        a0 += w * b2f(hv.x);
        a1 += w * b2f(hv.y);
        a2 += w * b2f(hv.z);
        a3 += w * b2f(hv.w);
    }
    const float inv = 1.0f / den;
    const int c = lane * 4;
    float v0 = a0 * inv + bias[c + 0];
    float v1 = a1 * inv + bias[c + 1];
    float v2 = a2 * inv + bias[c + 2];
    float v3 = a3 * inv + bias[c + 3];
    v0 = v0 > 0.f ? v0 : expm1f(v0);
    v1 = v1 > 0.f ? v1 : expm1f(v1);
    v2 = v2 > 0.f ? v2 : expm1f(v2);
    v3 = v3 > 0.f ? v3 : expm1f(v3);
    ushort4 o;
    o.x = f2b(v0); o.y = f2b(v1); o.z = f2b(v2); o.w = f2b(v3);
    *(ushort4*)(x2 + (size_t)d * FDIM + c) = o;
}

// ---------------------------------------------------------------------------
extern "C" void kernel_launch(void* const* d_in, const int* in_sizes, int n_in,
                              void* d_out, int out_size, void* d_ws, size_t ws_size,
                              hipStream_t stream) {
    const float* x   = (const float*)d_in[0];
    const int*   ei  = (const int*)d_in[1];
    const float* W1  = (const float*)d_in[3];
    const float* as1 = (const float*)d_in[4];
    const float* ad1 = (const float*)d_in[5];
    const float* b1  = (const float*)d_in[6];
    const float* W2  = (const float*)d_in[7];
    const float* as2 = (const float*)d_in[8];
    const float* ad2 = (const float*)d_in[9];
    const float* b2  = (const float*)d_in[10];
    const float* fcW = (const float*)d_in[11];
    const float* fcb = (const float*)d_in[12];
    float* out = (float*)d_out;

    const int n = in_sizes[0] / FDIM;   // 50000
    const int E = in_sizes[1] / 2;      // 800000
    const int Etot = E + n;
    const int* srcp = ei;
    const int* dstp = ei + E;
    const int nbk = (n + 31) / 32;      // 1563 buckets

    // -------- workspace carve (256B aligned), ~62 MB --------
    char* ws = (char*)d_ws;
    size_t off_b = 0;
    auto carve = [&](size_t bytes) -> char* {
        char* p = ws + off_b;
        off_b += (bytes + 255) & ~(size_t)255;
        return p;
    };
    unsigned short* xb = (unsigned short*)carve((size_t)n * FDIM * 2);  // also x2
    unsigned short* h  = (unsigned short*)carve((size_t)n * FDIM * 2);
    float* als  = (float*)carve((size_t)n * HEADS * 4);
    float* ald  = (float*)carve((size_t)n * HEADS * 4);
    int* deg    = (int*)carve((size_t)n * 4);
    int* offs   = (int*)carve((size_t)(n + 1) * 4);
    int* cnt    = (int*)carve((size_t)NBK_MAX * 128 * 4);   // 1 MB, k-major
    int* bHist  = (int*)carve((size_t)NBK_MAX * 4);
    int* bOffs  = (int*)carve((size_t)(NBK_MAX + 1) * 4);
    unsigned int* pairs = (unsigned int*)carve((size_t)Etot * 4);
    int* csr_src = (int*)carve((size_t)Etot * 4);
    unsigned short* Wt1  = (unsigned short*)carve(FDIM * FDIM * 2);
    unsigned short* Wt2  = (unsigned short*)carve(FDIM * FDIM * 2);
    unsigned short* fcWt = (unsigned short*)carve(64 * FDIM * 2);
    unsigned short* x2 = xb;   // alias: xb dead after layer-1 GEMM

    const int mblocks = (n + 63) / 64;       // BM=64 -> 782
    const int nx4 = n * FDIM / 4;
    const int cvtblocks = (nx4 + 2 * FDIM * FDIM + FDIM * 64 + 255) / 256;

    // -------- CSR build (atomic-free counting sort) --------
    cnt_hist<<<128, 1024, 0, stream>>>(dstp, cnt, E, Etot, nbk);
    cvt_scan<<<cvtblocks + nbk, 256, 0, stream>>>(
        x, xb, W1, Wt1, W2, Wt2, fcW, fcWt, cnt, bHist, nx4, cvtblocks);
    bscan<<<1, 64, 0, stream>>>(bHist, bOffs, nbk);
    bscatter<<<128, 1024, 0, stream>>>(srcp, dstp, bOffs, cnt, pairs, E, Etot, nbk);
    csr_build<<<nbk, 128, 0, stream>>>(pairs, bOffs, offs, deg, csr_src, n);

    // -------- layer 1 --------
    gemm_bt_k256<64, 128, false, true><<<mblocks * 2, 256, 0, stream>>>(
        xb, Wt1, h, nullptr, as1, ad1, als, ald, n, FDIM);
    gat_gather<<<(n + 3) / 4, 256, 0, stream>>>(
        offs, deg, csr_src, als, ald, h, b1, x2, n);

    // -------- layer 2 --------
    gemm_bt_k256<64, 128, false, true><<<mblocks * 2, 256, 0, stream>>>(
        x2, Wt2, h, nullptr, as2, ad2, als, ald, n, FDIM);
    gat_gather<<<(n + 3) / 4, 256, 0, stream>>>(
        offs, deg, csr_src, als, ald, h, b2, x2, n);

    // -------- final FC: out[n][64] = x2 @ fcW + fcb (FP32 out) --------
    gemm_bt_k256<64, 64, true, false><<<mblocks, 256, 0, stream>>>(
        x2, fcWt, out, fcb, nullptr, nullptr, nullptr, nullptr, n, 64);
}